// Round 1
// baseline (3509.049 us; speedup 1.0000x reference)
//
#include <hip/hip_runtime.h>

// RuleRNN: 10 GRU steps + 8 attention hops, B=8192 D=512 R=4000.
// All GEMMs via split-fp16 MFMA (x = hi + lo, 3 products) for ~22-bit effective
// input mantissa -> survives the attention feedback error amplification.
// fp32 elementwise / softmax. m97-style GEMM: 128x128 tile, BK=32, 4 waves,
// linear LDS + global_load_lds(16B).

typedef _Float16 f16;
typedef _Float16 f16x8 __attribute__((ext_vector_type(8)));
typedef _Float16 f16x4 __attribute__((ext_vector_type(4)));
typedef float    f32x4 __attribute__((ext_vector_type(4)));

constexpr int BATCH = 8192;
constexpr int DDIM  = 512;
constexpr int D3    = 1536;
constexpr int NRELT = 4000;   // true relation count
constexpr int NRELP = 4096;   // padded (zeros)
constexpr int NHOP  = 8;

#define MFMA16(a,b,c) __builtin_amdgcn_mfma_f32_16x16x32_f16((a),(b),(c),0,0,0)

__device__ __forceinline__ void gll16(const void* g, void* l) {
  __builtin_amdgcn_global_load_lds(
      (const __attribute__((address_space(1))) unsigned int*)g,
      (__attribute__((address_space(3))) unsigned int*)l, 16, 0, 0);
}

// ---------------- prep kernels ----------------
__global__ __launch_bounds__(256) void k_split(const float* __restrict__ src,
                                               f16* __restrict__ hi, f16* __restrict__ lo, int n) {
  int i = blockIdx.x * 256 + threadIdx.x;
  if (i >= n) return;
  float v = src[i];
  f16 h = (f16)v;
  hi[i] = h;
  lo[i] = (f16)(v - (float)h);
}

// relation -> padded [4096][512] hi/lo and transposed [512][4096] hi/lo
__global__ __launch_bounds__(256) void k_prep_rel(const float* __restrict__ rel,
    f16* __restrict__ rhi, f16* __restrict__ rlo,
    f16* __restrict__ thi, f16* __restrict__ tlo) {
  int i = blockIdx.x * 256 + threadIdx.x;
  if (i >= NRELP * DDIM) return;
  int r = i >> 9, d = i & 511;
  float v = (r < NRELT) ? rel[i] : 0.f;
  f16 h = (f16)v, l = (f16)(v - (float)h);
  rhi[i] = h; rlo[i] = l;
  thi[(size_t)d * NRELP + r] = h;
  tlo[(size_t)d * NRELP + r] = l;
}

// gi_eos[o] = sum_d W_ih[o][d] * eos[d]   (full fp32; bias added in gate kernel)
__global__ __launch_bounds__(64) void k_gieos(const float* __restrict__ W,
                                              const float* __restrict__ eos,
                                              float* __restrict__ out) {
  int o = blockIdx.x;
  float s = 0.f;
  for (int i = threadIdx.x; i < DDIM; i += 64) s += W[(size_t)o * DDIM + i] * eos[i];
  for (int off = 32; off; off >>= 1) s += __shfl_xor(s, off);
  if (threadIdx.x == 0) out[o] = s;
}

// ---------------- GEMM: C[M,N] = A[M,K] * B[N,K]^T, split-fp16, fp32 acc ----
// AFROMS: A tile generated on the fly as P = exp(S - rowm)*rowil (softmax probs)
// EPI==0: plain store to Cout (cols < nbound). EPI==1: subgoal epilogue:
//         store to d_out[b][hop][d] + write fp16 hi/lo splits.
template<bool AFROMS, int EPI>
__global__ __launch_bounds__(256, 2)
void gemm_k(const f16* __restrict__ Ahi, const f16* __restrict__ Alo, int lda,
            const f16* __restrict__ Bhi, const f16* __restrict__ Blo, int ldb,
            float* __restrict__ Cout, int ldc, int nbound, int K,
            const float* __restrict__ S, const float* __restrict__ rowm,
            const float* __restrict__ rowil,
            float* __restrict__ outp, f16* __restrict__ shi, f16* __restrict__ slo,
            int hop)
{
  __shared__ f16 lAh[128][32];
  __shared__ f16 lAl[128][32];
  __shared__ f16 lBh[128][32];
  __shared__ f16 lBl[128][32];

  const int tid  = threadIdx.x;
  const int lane = tid & 63;
  const int wave = tid >> 6;
  const int wm = wave >> 1;
  const int wn = wave & 1;
  const int m0 = blockIdx.x * 128;
  const int n0 = blockIdx.y * 128;
  const int rb = lane & 15;
  const int ko = (lane >> 4) * 8;

  f32x4 acc[4][4] = {};

  for (int k0 = 0; k0 < K; k0 += 32) {
    // stage B hi/lo: 8 chunks of 16 rows; wave handles chunks {wave, wave+4}
    #pragma unroll
    for (int c = 0; c < 2; ++c) {
      const int ch = wave + c * 4;
      const int r  = ch * 16 + (lane >> 2);
      const size_t goff = (size_t)(n0 + r) * ldb + k0 + (lane & 3) * 8;
      gll16(Bhi + goff, &lBh[ch * 16][0]);
      gll16(Blo + goff, &lBl[ch * 16][0]);
    }
    if constexpr (!AFROMS) {
      #pragma unroll
      for (int c = 0; c < 2; ++c) {
        const int ch = wave + c * 4;
        const int r  = ch * 16 + (lane >> 2);
        const size_t goff = (size_t)(m0 + r) * lda + k0 + (lane & 3) * 8;
        gll16(Ahi + goff, &lAh[ch * 16][0]);
        gll16(Alo + goff, &lAl[ch * 16][0]);
      }
    } else {
      // A tile = softmax(P) computed from fp32 scores, split to hi/lo
      #pragma unroll
      for (int it = 0; it < 4; ++it) {
        const int cid = tid + it * 256;        // 0..1023
        const int row = cid >> 3;              // 0..127
        const int c4  = (cid & 7) * 4;         // 0..28
        const int kg  = k0 + c4;
        const int gr  = m0 + row;
        f32x4 s4 = *(const f32x4*)(S + (size_t)gr * NRELP + kg);
        const float mr = rowm[gr];
        const float il = rowil[gr];
        f16x4 vh, vl;
        #pragma unroll
        for (int j = 0; j < 4; ++j) {
          float pv = (kg + j < NRELT) ? __expf(s4[j] - mr) * il : 0.f;
          f16 ph = (f16)pv;
          vh[j] = ph;
          vl[j] = (f16)(pv - (float)ph);
        }
        *(f16x4*)&lAh[row][c4] = vh;
        *(f16x4*)&lAl[row][c4] = vl;
      }
    }
    __syncthreads();

    f16x8 ah[4], al[4], bh[4], bl[4];
    #pragma unroll
    for (int f = 0; f < 4; ++f) {
      ah[f] = *(const f16x8*)&lAh[wm * 64 + f * 16 + rb][ko];
      al[f] = *(const f16x8*)&lAl[wm * 64 + f * 16 + rb][ko];
      bh[f] = *(const f16x8*)&lBh[wn * 64 + f * 16 + rb][ko];
      bl[f] = *(const f16x8*)&lBl[wn * 64 + f * 16 + rb][ko];
    }
    #pragma unroll
    for (int fm = 0; fm < 4; ++fm)
      #pragma unroll
      for (int fn = 0; fn < 4; ++fn) {
        acc[fm][fn] = MFMA16(ah[fm], bh[fn], acc[fm][fn]);
        acc[fm][fn] = MFMA16(ah[fm], bl[fn], acc[fm][fn]);
        acc[fm][fn] = MFMA16(al[fm], bh[fn], acc[fm][fn]);
      }
    __syncthreads();
  }

  // epilogue: C/D layout col = lane&15, row = (lane>>4)*4 + r  [verified m89/m91]
  #pragma unroll
  for (int fm = 0; fm < 4; ++fm)
    #pragma unroll
    for (int fn = 0; fn < 4; ++fn)
      #pragma unroll
      for (int r = 0; r < 4; ++r) {
        const int gr = m0 + wm * 64 + fm * 16 + (lane >> 4) * 4 + r;
        const int gc = n0 + wn * 64 + fn * 16 + rb;
        const float v = acc[fm][fn][r];
        if (gc < nbound) {
          if constexpr (EPI == 0) {
            Cout[(size_t)gr * ldc + gc] = v;
          } else {
            outp[(size_t)gr * (NHOP * DDIM) + (size_t)hop * DDIM + gc] = v;
            const f16 ph = (f16)v;
            shi[(size_t)gr * DDIM + gc] = ph;
            slo[(size_t)gr * DDIM + gc] = (f16)(v - (float)ph);
          }
        }
      }
}

// ---------------- softmax row stats: max and 1/sum(exp) over 4000 cols -------
__global__ __launch_bounds__(256)
void k_rowstat(const float* __restrict__ S, float* __restrict__ rowm,
               float* __restrict__ rowil) {
  const int row = blockIdx.x;
  const float* p = S + (size_t)row * NRELP;
  const int tid = threadIdx.x, lane = tid & 63, wv = tid >> 6;
  __shared__ float redm[4], reds[4];
  float mx = -3.402823e38f;
  for (int c = tid; c < NRELT / 4; c += 256) {
    f32x4 v = *(const f32x4*)(p + c * 4);
    mx = fmaxf(fmaxf(fmaxf(mx, v[0]), fmaxf(v[1], v[2])), v[3]);
  }
  for (int o = 32; o; o >>= 1) mx = fmaxf(mx, __shfl_xor(mx, o));
  if (lane == 0) redm[wv] = mx;
  __syncthreads();
  mx = fmaxf(fmaxf(redm[0], redm[1]), fmaxf(redm[2], redm[3]));
  float s = 0.f;
  for (int c = tid; c < NRELT / 4; c += 256) {
    f32x4 v = *(const f32x4*)(p + c * 4);
    s += __expf(v[0] - mx) + __expf(v[1] - mx) + __expf(v[2] - mx) + __expf(v[3] - mx);
  }
  for (int o = 32; o; o >>= 1) s += __shfl_xor(s, o);
  if (lane == 0) reds[wv] = s;
  __syncthreads();
  if (tid == 0) {
    rowm[row]  = mx;
    rowil[row] = 1.f / (reds[0] + reds[1] + reds[2] + reds[3]);
  }
}

// ---------------- GRU gate fusion -------------------------------------------
// h = (1-z)*tanh(i_n + r*h_n) + z*h_prev ; writes h fp32 + hi/lo splits.
// gi==nullptr -> use broadcast vector givec (eos step). gh==nullptr -> gh=0
// (h_prev = 0 step). Biases always added here.
__global__ __launch_bounds__(256)
void k_gates(const float* __restrict__ gi, const float* __restrict__ givec,
             const float* __restrict__ gh,
             const float* __restrict__ bih, const float* __restrict__ bhh,
             const float* __restrict__ hin, float* __restrict__ hout,
             f16* __restrict__ hhi, f16* __restrict__ hlo)
{
  const int idx = blockIdx.x * 256 + threadIdx.x;   // over BATCH*DDIM/4
  const int b  = idx >> 7;
  const int d4 = (idx & 127) * 4;
  f32x4 ir, iz, inn;
  if (gi) {
    const float* g = gi + (size_t)b * D3 + d4;
    ir  = *(const f32x4*)(g);
    iz  = *(const f32x4*)(g + DDIM);
    inn = *(const f32x4*)(g + 2 * DDIM);
  } else {
    ir  = *(const f32x4*)(givec + d4);
    iz  = *(const f32x4*)(givec + DDIM + d4);
    inn = *(const f32x4*)(givec + 2 * DDIM + d4);
  }
  ir  += *(const f32x4*)(bih + d4);
  iz  += *(const f32x4*)(bih + DDIM + d4);
  inn += *(const f32x4*)(bih + 2 * DDIM + d4);
  f32x4 hr = {0.f, 0.f, 0.f, 0.f}, hz = {0.f, 0.f, 0.f, 0.f}, hn = {0.f, 0.f, 0.f, 0.f};
  if (gh) {
    const float* g = gh + (size_t)b * D3 + d4;
    hr = *(const f32x4*)(g);
    hz = *(const f32x4*)(g + DDIM);
    hn = *(const f32x4*)(g + 2 * DDIM);
  }
  hr += *(const f32x4*)(bhh + d4);
  hz += *(const f32x4*)(bhh + DDIM + d4);
  hn += *(const f32x4*)(bhh + 2 * DDIM + d4);
  f32x4 hp = {0.f, 0.f, 0.f, 0.f};
  if (hin) hp = *(const f32x4*)(hin + (size_t)b * DDIM + d4);
  f32x4 hv; f16x4 vh, vl;
  #pragma unroll
  for (int j = 0; j < 4; ++j) {
    const float r = 1.f / (1.f + __expf(-(ir[j] + hr[j])));
    const float z = 1.f / (1.f + __expf(-(iz[j] + hz[j])));
    const float n = tanhf(inn[j] + r * hn[j]);
    const float h = (1.f - z) * n + z * hp[j];
    hv[j] = h;
    const f16 ph = (f16)h;
    vh[j] = ph;
    vl[j] = (f16)(h - (float)ph);
  }
  *(f32x4*)(hout + (size_t)b * DDIM + d4) = hv;
  *(f16x4*)(hhi + (size_t)b * DDIM + d4) = vh;
  *(f16x4*)(hlo + (size_t)b * DDIM + d4) = vl;
}

__global__ __launch_bounds__(256) void k_ones(float* __restrict__ o, int n) {
  int i = blockIdx.x * 256 + threadIdx.x;
  if (i < n) o[i] = 1.0f;
}

// ---------------- host ------------------------------------------------------
extern "C" void kernel_launch(void* const* d_in, const int* in_sizes, int n_in,
                              void* d_out, int out_size, void* d_ws, size_t ws_size,
                              hipStream_t stream)
{
  const float* query = (const float*)d_in[0];
  const float* W_ih  = (const float*)d_in[1];
  const float* W_hh  = (const float*)d_in[2];
  const float* b_ih  = (const float*)d_in[3];
  const float* b_hh  = (const float*)d_in[4];
  const float* rel   = (const float*)d_in[5];
  const float* eos   = (const float*)d_in[6];
  float* out = (float*)d_out;
  (void)in_sizes; (void)n_in; (void)out_size; (void)ws_size;

  // workspace layout (~198 MB)
  char* w = (char*)d_ws;
  float* Sb    = (float*)w; w += (size_t)BATCH * NRELP * 4;   // 128MB; gi/gh reuse
  float* hbuf  = (float*)w; w += (size_t)BATCH * DDIM * 4;
  f16* h_hi    = (f16*)w;   w += (size_t)BATCH * DDIM * 2;
  f16* h_lo    = (f16*)w;   w += (size_t)BATCH * DDIM * 2;
  f16* x_hi    = (f16*)w;   w += (size_t)BATCH * DDIM * 2;    // query, then subgoal
  f16* x_lo    = (f16*)w;   w += (size_t)BATCH * DDIM * 2;
  f16* wih_hi  = (f16*)w;   w += (size_t)D3 * DDIM * 2;
  f16* wih_lo  = (f16*)w;   w += (size_t)D3 * DDIM * 2;
  f16* whh_hi  = (f16*)w;   w += (size_t)D3 * DDIM * 2;
  f16* whh_lo  = (f16*)w;   w += (size_t)D3 * DDIM * 2;
  f16* rel_hi  = (f16*)w;   w += (size_t)NRELP * DDIM * 2;
  f16* rel_lo  = (f16*)w;   w += (size_t)NRELP * DDIM * 2;
  f16* relT_hi = (f16*)w;   w += (size_t)DDIM * NRELP * 2;
  f16* relT_lo = (f16*)w;   w += (size_t)DDIM * NRELP * 2;
  float* rowm  = (float*)w; w += (size_t)BATCH * 4;
  float* rowil = (float*)w; w += (size_t)BATCH * 4;
  float* gieos = (float*)w; w += (size_t)D3 * 4;
  float* gi = Sb;                         // S is dead when gi/gh are live
  float* gh = Sb + (size_t)BATCH * D3;

  // prep
  k_split<<<(BATCH * DDIM + 255) / 256, 256, 0, stream>>>(query, x_hi, x_lo, BATCH * DDIM);
  k_split<<<(D3 * DDIM + 255) / 256, 256, 0, stream>>>(W_ih, wih_hi, wih_lo, D3 * DDIM);
  k_split<<<(D3 * DDIM + 255) / 256, 256, 0, stream>>>(W_hh, whh_hi, whh_lo, D3 * DDIM);
  k_prep_rel<<<(NRELP * DDIM + 255) / 256, 256, 0, stream>>>(rel, rel_hi, rel_lo, relT_hi, relT_lo);
  k_gieos<<<D3, 64, 0, stream>>>(W_ih, eos, gieos);

  const int ggrid = BATCH * DDIM / 4 / 256;

  // step A: h1 = GRU(query, 0)  (gh = b_hh only, h_prev = 0)
  gemm_k<false, 0><<<dim3(64, 12), 256, 0, stream>>>(x_hi, x_lo, DDIM, wih_hi, wih_lo, DDIM,
      gi, D3, D3, DDIM, nullptr, nullptr, nullptr, nullptr, nullptr, nullptr, 0);
  k_gates<<<ggrid, 256, 0, stream>>>(gi, nullptr, nullptr, b_ih, b_hh, nullptr, hbuf, h_hi, h_lo);

  // step B: h = GRU(eos, h1)  (gi = broadcast precomputed vector)
  gemm_k<false, 0><<<dim3(64, 12), 256, 0, stream>>>(h_hi, h_lo, DDIM, whh_hi, whh_lo, DDIM,
      gh, D3, D3, DDIM, nullptr, nullptr, nullptr, nullptr, nullptr, nullptr, 0);
  k_gates<<<ggrid, 256, 0, stream>>>(nullptr, gieos, gh, b_ih, b_hh, hbuf, hbuf, h_hi, h_lo);

  for (int hop = 0; hop < NHOP; ++hop) {
    // score = h @ relation^T  -> S fp32 [8192][4096], valid cols < 4000
    gemm_k<false, 0><<<dim3(64, 32), 256, 0, stream>>>(h_hi, h_lo, DDIM, rel_hi, rel_lo, DDIM,
        Sb, NRELP, NRELT, DDIM, nullptr, nullptr, nullptr, nullptr, nullptr, nullptr, 0);
    k_rowstat<<<BATCH, 256, 0, stream>>>(Sb, rowm, rowil);
    // subgoal = softmax(S) @ relation -> d_out[:,hop,:] + x_hi/x_lo splits
    gemm_k<true, 1><<<dim3(64, 4), 256, 0, stream>>>(nullptr, nullptr, 0, relT_hi, relT_lo, NRELP,
        nullptr, 0, DDIM, NRELP, Sb, rowm, rowil, out, x_hi, x_lo, hop);
    // GRU: gi = subgoal @ W_ih^T ; gh = h @ W_hh^T ; gates
    gemm_k<false, 0><<<dim3(64, 12), 256, 0, stream>>>(x_hi, x_lo, DDIM, wih_hi, wih_lo, DDIM,
        gi, D3, D3, DDIM, nullptr, nullptr, nullptr, nullptr, nullptr, nullptr, 0);
    gemm_k<false, 0><<<dim3(64, 12), 256, 0, stream>>>(h_hi, h_lo, DDIM, whh_hi, whh_lo, DDIM,
        gh, D3, D3, DDIM, nullptr, nullptr, nullptr, nullptr, nullptr, nullptr, 0);
    k_gates<<<ggrid, 256, 0, stream>>>(gi, nullptr, gh, b_ih, b_hh, hbuf, hbuf, h_hi, h_lo);
  }

  // masks = 1.0
  k_ones<<<(BATCH * NHOP + 255) / 256, 256, 0, stream>>>(out + (size_t)BATCH * NHOP * DDIM, BATCH * NHOP);
}

// Round 3
// 3300.407 us; speedup vs baseline: 1.0632x; 1.0632x over previous
//
#include <hip/hip_runtime.h>

// RuleRNN: 10 GRU steps + 8 attention hops, B=8192 D=512 R=4000.
// All GEMMs: split-fp16 MFMA, 3 products (hi*hi + hi*lo + lo*hi), fp32 acc.
// Round 3: score GEMM writes S as f16 hi/lo planes; softmax converts S->P
// in place (P also hi/lo); subgoal = standard staged 3-product GEMM split-K=4.

typedef _Float16 f16;
typedef _Float16 f16x8 __attribute__((ext_vector_type(8)));
typedef _Float16 f16x4 __attribute__((ext_vector_type(4)));
typedef float    f32x4 __attribute__((ext_vector_type(4)));

constexpr int BATCH = 8192;
constexpr int DDIM  = 512;
constexpr int D3    = 1536;
constexpr int NRELT = 4000;   // true relation count
constexpr int NRELP = 4096;   // padded (zeros)
constexpr int NHOP  = 8;

#define MFMA16(a,b,c) __builtin_amdgcn_mfma_f32_16x16x32_f16((a),(b),(c),0,0,0)

__device__ __forceinline__ void gll16(const void* g, void* l) {
  __builtin_amdgcn_global_load_lds(
      (const __attribute__((address_space(1))) unsigned int*)g,
      (__attribute__((address_space(3))) unsigned int*)l, 16, 0, 0);
}

// ---------------- prep kernels ----------------
__global__ __launch_bounds__(256) void k_split(const float* __restrict__ src,
                                               f16* __restrict__ hi, f16* __restrict__ lo, int n) {
  int i = blockIdx.x * 256 + threadIdx.x;
  if (i >= n) return;
  float v = src[i];
  f16 h = (f16)v;
  hi[i] = h;
  lo[i] = (f16)(v - (float)h);
}

// relation -> padded [4096][512] hi/lo and transposed [512][4096] hi/lo
__global__ __launch_bounds__(256) void k_prep_rel(const float* __restrict__ rel,
    f16* __restrict__ rhi, f16* __restrict__ rlo,
    f16* __restrict__ thi, f16* __restrict__ tlo) {
  int i = blockIdx.x * 256 + threadIdx.x;
  if (i >= NRELP * DDIM) return;
  int r = i >> 9, d = i & 511;
  float v = (r < NRELT) ? rel[i] : 0.f;
  f16 h = (f16)v, l = (f16)(v - (float)h);
  rhi[i] = h; rlo[i] = l;
  thi[(size_t)d * NRELP + r] = h;
  tlo[(size_t)d * NRELP + r] = l;
}

// gi_eos[o] = sum_d W_ih[o][d] * eos[d]   (full fp32; bias added in gate kernel)
__global__ __launch_bounds__(64) void k_gieos(const float* __restrict__ W,
                                              const float* __restrict__ eos,
                                              float* __restrict__ out) {
  int o = blockIdx.x;
  float s = 0.f;
  for (int i = threadIdx.x; i < DDIM; i += 64) s += W[(size_t)o * DDIM + i] * eos[i];
  for (int off = 32; off; off >>= 1) s += __shfl_xor(s, off);
  if (threadIdx.x == 0) out[o] = s;
}

// ---------------- GEMM: C[M,N] = A[M,K] * B[N,K]^T, fp32 acc ----------------
// 3 split products: Ahi*Bhi + Ahi*Blo + Alo*Bhi.
// EPI=0: fp32 store to Cout. EPI=1: split f16 hi/lo store to Chi/Clo.
// Split-K via blockIdx.z (each z: K contiguous k's, own C plane).
template<int EPI>
__global__ __launch_bounds__(256, 2)
void gemm_k(const f16* __restrict__ Ahi, const f16* __restrict__ Alo, int lda,
            const f16* __restrict__ Bhi, const f16* __restrict__ Blo, int ldb,
            float* __restrict__ Cout, f16* __restrict__ Chi, f16* __restrict__ Clo,
            int ldc, int K)
{
  __shared__ f16 lAh[128][32];
  __shared__ f16 lAl[128][32];
  __shared__ f16 lBh[128][32];
  __shared__ f16 lBl[128][32];

  const int tid  = threadIdx.x;
  const int lane = tid & 63;
  const int wave = tid >> 6;
  const int wm = wave >> 1;
  const int wn = wave & 1;
  const int m0 = blockIdx.x * 128;
  const int n0 = blockIdx.y * 128;
  const int rb = lane & 15;
  const int ko = (lane >> 4) * 8;

  const int kst = blockIdx.z * K;
  Cout += (size_t)blockIdx.z * (size_t)gridDim.x * 128 * (size_t)ldc;

  f32x4 acc[4][4] = {};

  for (int k0 = kst; k0 < kst + K; k0 += 32) {
    #pragma unroll
    for (int c = 0; c < 2; ++c) {
      const int ch = wave + c * 4;
      const int r  = ch * 16 + (lane >> 2);
      const size_t goff = (size_t)(n0 + r) * ldb + k0 + (lane & 3) * 8;
      gll16(Bhi + goff, &lBh[ch * 16][0]);
      gll16(Blo + goff, &lBl[ch * 16][0]);
    }
    #pragma unroll
    for (int c = 0; c < 2; ++c) {
      const int ch = wave + c * 4;
      const int r  = ch * 16 + (lane >> 2);
      const size_t goff = (size_t)(m0 + r) * lda + k0 + (lane & 3) * 8;
      gll16(Ahi + goff, &lAh[ch * 16][0]);
      gll16(Alo + goff, &lAl[ch * 16][0]);
    }
    __syncthreads();

    f16x8 ah[4], al[4], bh[4], bl[4];
    #pragma unroll
    for (int f = 0; f < 4; ++f) {
      ah[f] = *(const f16x8*)&lAh[wm * 64 + f * 16 + rb][ko];
      al[f] = *(const f16x8*)&lAl[wm * 64 + f * 16 + rb][ko];
      bh[f] = *(const f16x8*)&lBh[wn * 64 + f * 16 + rb][ko];
      bl[f] = *(const f16x8*)&lBl[wn * 64 + f * 16 + rb][ko];
    }
    #pragma unroll
    for (int fm = 0; fm < 4; ++fm)
      #pragma unroll
      for (int fn = 0; fn < 4; ++fn) {
        acc[fm][fn] = MFMA16(ah[fm], bh[fn], acc[fm][fn]);
        acc[fm][fn] = MFMA16(ah[fm], bl[fn], acc[fm][fn]);
        acc[fm][fn] = MFMA16(al[fm], bh[fn], acc[fm][fn]);
      }
    __syncthreads();
  }

  // epilogue: C/D layout col = lane&15, row = (lane>>4)*4 + r  [verified m89/m91]
  #pragma unroll
  for (int fm = 0; fm < 4; ++fm)
    #pragma unroll
    for (int fn = 0; fn < 4; ++fn)
      #pragma unroll
      for (int r = 0; r < 4; ++r) {
        const int gr = m0 + wm * 64 + fm * 16 + (lane >> 4) * 4 + r;
        const int gc = n0 + wn * 64 + fn * 16 + rb;
        const float v = acc[fm][fn][r];
        if constexpr (EPI == 0) {
          Cout[(size_t)gr * ldc + gc] = v;
        } else {
          const f16 vh = (f16)v;
          Chi[(size_t)gr * ldc + gc] = vh;
          Clo[(size_t)gr * ldc + gc] = (f16)(v - (float)vh);
        }
      }
}

// ---------------- softmax: S planes (f16 hi/lo) -> P planes in place --------
__global__ __launch_bounds__(256)
void k_softmax(f16* __restrict__ Shi, f16* __restrict__ Slo) {
  const int row = blockIdx.x;
  f16* phi = Shi + (size_t)row * NRELP;
  f16* plo = Slo + (size_t)row * NRELP;
  const int tid = threadIdx.x, lane = tid & 63, wv = tid >> 6;
  const int ng = (tid < 232) ? 4 : 3;     // 1000 groups of 4 cols
  f32x4 v[4];
  float mx = -3.402823e38f;
  #pragma unroll
  for (int i = 0; i < 4; ++i)
    if (i < ng) {
      f16x4 hv = *(const f16x4*)(phi + (tid + 256 * i) * 4);
      f16x4 lv = *(const f16x4*)(plo + (tid + 256 * i) * 4);
      #pragma unroll
      for (int j = 0; j < 4; ++j) v[i][j] = (float)hv[j] + (float)lv[j];
      mx = fmaxf(fmaxf(fmaxf(mx, v[i][0]), fmaxf(v[i][1], v[i][2])), v[i][3]);
    }
  float l = 0.f;
  #pragma unroll
  for (int i = 0; i < 4; ++i)
    if (i < ng)
      l += __expf(v[i][0] - mx) + __expf(v[i][1] - mx)
         + __expf(v[i][2] - mx) + __expf(v[i][3] - mx);
  #pragma unroll
  for (int off = 1; off < 64; off <<= 1) {
    float om = __shfl_xor(mx, off), ol = __shfl_xor(l, off);
    float nm = fmaxf(mx, om);
    l = l * __expf(mx - nm) + ol * __expf(om - nm);
    mx = nm;
  }
  __shared__ float sm[4], sl[4];
  if (lane == 0) { sm[wv] = mx; sl[wv] = l; }
  __syncthreads();
  const float fm = fmaxf(fmaxf(sm[0], sm[1]), fmaxf(sm[2], sm[3]));
  const float fl = sl[0] * __expf(sm[0] - fm) + sl[1] * __expf(sm[1] - fm)
                 + sl[2] * __expf(sm[2] - fm) + sl[3] * __expf(sm[3] - fm);
  const float il = 1.f / fl;
  #pragma unroll
  for (int i = 0; i < 4; ++i)
    if (i < ng) {
      f16x4 oh, ol;
      #pragma unroll
      for (int j = 0; j < 4; ++j) {
        const float pv = __expf(v[i][j] - fm) * il;
        const f16 ph = (f16)pv;
        oh[j] = ph;
        ol[j] = (f16)(pv - (float)ph);
      }
      *(f16x4*)(phi + (tid + 256 * i) * 4) = oh;
      *(f16x4*)(plo + (tid + 256 * i) * 4) = ol;
    }
  if (tid < 24) {   // zero pad cols 4000..4095 in both planes
    f16x4 z = {(f16)0.f, (f16)0.f, (f16)0.f, (f16)0.f};
    *(f16x4*)(phi + (1000 + tid) * 4) = z;
    *(f16x4*)(plo + (1000 + tid) * 4) = z;
  }
}

// ---------------- split-K reduce + subgoal epilogue -------------------------
__global__ __launch_bounds__(256)
void k_subred(const float* __restrict__ Cp, float* __restrict__ outp,
              f16* __restrict__ xhi, f16* __restrict__ xlo, int hop) {
  const int idx = blockIdx.x * 256 + threadIdx.x;    // BATCH*DDIM/4
  const int b = idx >> 7, d4 = (idx & 127) * 4;
  const size_t o = (size_t)b * DDIM + d4;
  f32x4 s = *(const f32x4*)(Cp + o);
  s += *(const f32x4*)(Cp + (size_t)BATCH * DDIM + o);
  s += *(const f32x4*)(Cp + 2 * (size_t)BATCH * DDIM + o);
  s += *(const f32x4*)(Cp + 3 * (size_t)BATCH * DDIM + o);
  *(f32x4*)(outp + (size_t)b * (NHOP * DDIM) + (size_t)hop * DDIM + d4) = s;
  f16x4 vh, vl;
  #pragma unroll
  for (int j = 0; j < 4; ++j) {
    const f16 ph = (f16)s[j];
    vh[j] = ph;
    vl[j] = (f16)(s[j] - (float)ph);
  }
  *(f16x4*)(xhi + o) = vh;
  *(f16x4*)(xlo + o) = vl;
}

// ---------------- GRU gate fusion -------------------------------------------
__global__ __launch_bounds__(256)
void k_gates(const float* __restrict__ gi, const float* __restrict__ givec,
             const float* __restrict__ gh,
             const float* __restrict__ bih, const float* __restrict__ bhh,
             const float* __restrict__ hin, float* __restrict__ hout,
             f16* __restrict__ hhi, f16* __restrict__ hlo)
{
  const int idx = blockIdx.x * 256 + threadIdx.x;   // over BATCH*DDIM/4
  const int b  = idx >> 7;
  const int d4 = (idx & 127) * 4;
  f32x4 ir, iz, inn;
  if (gi) {
    const float* g = gi + (size_t)b * D3 + d4;
    ir  = *(const f32x4*)(g);
    iz  = *(const f32x4*)(g + DDIM);
    inn = *(const f32x4*)(g + 2 * DDIM);
  } else {
    ir  = *(const f32x4*)(givec + d4);
    iz  = *(const f32x4*)(givec + DDIM + d4);
    inn = *(const f32x4*)(givec + 2 * DDIM + d4);
  }
  ir  += *(const f32x4*)(bih + d4);
  iz  += *(const f32x4*)(bih + DDIM + d4);
  inn += *(const f32x4*)(bih + 2 * DDIM + d4);
  f32x4 hr = {0.f, 0.f, 0.f, 0.f}, hz = {0.f, 0.f, 0.f, 0.f}, hn = {0.f, 0.f, 0.f, 0.f};
  if (gh) {
    const float* g = gh + (size_t)b * D3 + d4;
    hr = *(const f32x4*)(g);
    hz = *(const f32x4*)(g + DDIM);
    hn = *(const f32x4*)(g + 2 * DDIM);
  }
  hr += *(const f32x4*)(bhh + d4);
  hz += *(const f32x4*)(bhh + DDIM + d4);
  hn += *(const f32x4*)(bhh + 2 * DDIM + d4);
  f32x4 hp = {0.f, 0.f, 0.f, 0.f};
  if (hin) hp = *(const f32x4*)(hin + (size_t)b * DDIM + d4);
  f32x4 hv; f16x4 vh, vl;
  #pragma unroll
  for (int j = 0; j < 4; ++j) {
    const float r = 1.f / (1.f + __expf(-(ir[j] + hr[j])));
    const float z = 1.f / (1.f + __expf(-(iz[j] + hz[j])));
    const float n = tanhf(inn[j] + r * hn[j]);
    const float h = (1.f - z) * n + z * hp[j];
    hv[j] = h;
    const f16 ph = (f16)h;
    vh[j] = ph;
    vl[j] = (f16)(h - (float)ph);
  }
  *(f32x4*)(hout + (size_t)b * DDIM + d4) = hv;
  *(f16x4*)(hhi + (size_t)b * DDIM + d4) = vh;
  *(f16x4*)(hlo + (size_t)b * DDIM + d4) = vl;
}

__global__ __launch_bounds__(256) void k_ones(float* __restrict__ o, int n) {
  int i = blockIdx.x * 256 + threadIdx.x;
  if (i < n) o[i] = 1.0f;
}

// ---------------- host ------------------------------------------------------
extern "C" void kernel_launch(void* const* d_in, const int* in_sizes, int n_in,
                              void* d_out, int out_size, void* d_ws, size_t ws_size,
                              hipStream_t stream)
{
  const float* query = (const float*)d_in[0];
  const float* W_ih  = (const float*)d_in[1];
  const float* W_hh  = (const float*)d_in[2];
  const float* b_ih  = (const float*)d_in[3];
  const float* b_hh  = (const float*)d_in[4];
  const float* rel   = (const float*)d_in[5];
  const float* eos   = (const float*)d_in[6];
  float* out = (float*)d_out;
  (void)in_sizes; (void)n_in; (void)out_size; (void)ws_size;

  // workspace layout (~262 MB)
  char* w = (char*)d_ws;
  f16* SPhi    = (f16*)w;   w += (size_t)BATCH * NRELP * 2;   // 64MB S/P hi; gi/gh alias
  f16* SPlo    = (f16*)w;   w += (size_t)BATCH * NRELP * 2;   // 64MB S/P lo
  float* Cpart = (float*)w; w += (size_t)4 * BATCH * DDIM * 4;// 64MB split-K partials
  float* hbuf  = (float*)w; w += (size_t)BATCH * DDIM * 4;
  f16* h_hi    = (f16*)w;   w += (size_t)BATCH * DDIM * 2;
  f16* h_lo    = (f16*)w;   w += (size_t)BATCH * DDIM * 2;
  f16* x_hi    = (f16*)w;   w += (size_t)BATCH * DDIM * 2;    // query, then subgoal
  f16* x_lo    = (f16*)w;   w += (size_t)BATCH * DDIM * 2;
  f16* wih_hi  = (f16*)w;   w += (size_t)D3 * DDIM * 2;
  f16* wih_lo  = (f16*)w;   w += (size_t)D3 * DDIM * 2;
  f16* whh_hi  = (f16*)w;   w += (size_t)D3 * DDIM * 2;
  f16* whh_lo  = (f16*)w;   w += (size_t)D3 * DDIM * 2;
  f16* rel_hi  = (f16*)w;   w += (size_t)NRELP * DDIM * 2;
  f16* rel_lo  = (f16*)w;   w += (size_t)NRELP * DDIM * 2;
  f16* relT_hi = (f16*)w;   w += (size_t)DDIM * NRELP * 2;
  f16* relT_lo = (f16*)w;   w += (size_t)DDIM * NRELP * 2;
  float* gieos = (float*)w; w += (size_t)D3 * 4;
  float* gi = (float*)SPhi;               // S/P planes dead when gi/gh live
  float* gh = (float*)SPhi + (size_t)BATCH * D3;

  // prep
  k_split<<<(BATCH * DDIM + 255) / 256, 256, 0, stream>>>(query, x_hi, x_lo, BATCH * DDIM);
  k_split<<<(D3 * DDIM + 255) / 256, 256, 0, stream>>>(W_ih, wih_hi, wih_lo, D3 * DDIM);
  k_split<<<(D3 * DDIM + 255) / 256, 256, 0, stream>>>(W_hh, whh_hi, whh_lo, D3 * DDIM);
  k_prep_rel<<<(NRELP * DDIM + 255) / 256, 256, 0, stream>>>(rel, rel_hi, rel_lo, relT_hi, relT_lo);
  k_gieos<<<D3, 64, 0, stream>>>(W_ih, eos, gieos);

  const int ggrid = BATCH * DDIM / 4 / 256;

  // step A: h1 = GRU(query, 0)
  gemm_k<0><<<dim3(64, 12), 256, 0, stream>>>(x_hi, x_lo, DDIM, wih_hi, wih_lo, DDIM,
      gi, nullptr, nullptr, D3, DDIM);
  k_gates<<<ggrid, 256, 0, stream>>>(gi, nullptr, nullptr, b_ih, b_hh, nullptr, hbuf, h_hi, h_lo);

  // step B: h = GRU(eos, h1)
  gemm_k<0><<<dim3(64, 12), 256, 0, stream>>>(h_hi, h_lo, DDIM, whh_hi, whh_lo, DDIM,
      gh, nullptr, nullptr, D3, DDIM);
  k_gates<<<ggrid, 256, 0, stream>>>(nullptr, gieos, gh, b_ih, b_hh, hbuf, hbuf, h_hi, h_lo);

  for (int hop = 0; hop < NHOP; ++hop) {
    // score = h @ relation^T -> S as f16 hi/lo planes (pad cols exact 0)
    gemm_k<1><<<dim3(64, 32), 256, 0, stream>>>(h_hi, h_lo, DDIM, rel_hi, rel_lo, DDIM,
        nullptr, SPhi, SPlo, NRELP, DDIM);
    // P = softmax(S), hi/lo in place
    k_softmax<<<BATCH, 256, 0, stream>>>(SPhi, SPlo);
    // subgoal partials: P @ relT^T, 3 products, split-K=4
    gemm_k<0><<<dim3(64, 4, 4), 256, 0, stream>>>(SPhi, SPlo, NRELP,
        relT_hi, relT_lo, NRELP, Cpart, nullptr, nullptr, DDIM, NRELP / 4);
    // reduce partials -> d_out[:,hop,:] + x hi/lo splits
    k_subred<<<ggrid, 256, 0, stream>>>(Cpart, out, x_hi, x_lo, hop);
    // GRU: gi = subgoal @ W_ih^T ; gh = h @ W_hh^T ; gates
    gemm_k<0><<<dim3(64, 12), 256, 0, stream>>>(x_hi, x_lo, DDIM, wih_hi, wih_lo, DDIM,
        gi, nullptr, nullptr, D3, DDIM);
    gemm_k<0><<<dim3(64, 12), 256, 0, stream>>>(h_hi, h_lo, DDIM, whh_hi, whh_lo, DDIM,
        gh, nullptr, nullptr, D3, DDIM);
    k_gates<<<ggrid, 256, 0, stream>>>(gi, nullptr, gh, b_ih, b_hh, hbuf, hbuf, h_hi, h_lo);
  }

  // masks = 1.0
  k_ones<<<(BATCH * NHOP + 255) / 256, 256, 0, stream>>>(out + (size_t)BATCH * NHOP * DDIM, BATCH * NHOP);
}